// Round 9
// baseline (196.955 us; speedup 1.0000x reference)
//
#include <hip/hip_runtime.h>
#include <stdint.h>

#define SEQ     1024
// projT tail columns (fp32): Bp=0, Cp=128, dd_dt=256, dd_A=288, trap=320, ang=352  (width 384)

typedef __attribute__((ext_vector_type(8))) short short8;
typedef __attribute__((ext_vector_type(4))) float f4;

__device__ __forceinline__ short f2b(float f){
  union { float f; uint32_t u; } v; v.f = f;
  uint32_t r = (v.u + 0x7fffu + ((v.u >> 16) & 1u)) >> 16;
  return (short)(uint16_t)r;
}
__device__ __forceinline__ float b2f(uint16_t u){
  union { uint32_t u; float f; } v; v.u = ((uint32_t)u) << 16; return v.f;
}
__device__ __forceinline__ uint32_t pack2(float lo, float hi){
  return (uint32_t)(uint16_t)f2b(lo) | ((uint32_t)(uint16_t)f2b(hi) << 16);
}
__device__ __forceinline__ float softplus_f(float x){
  return x > 20.f ? x : log1pf(__expf(x));
}
// async global->LDS 16B/lane; lds dest must be wave-uniform base + lane*16 order
__device__ __forceinline__ void gload_lds16(const short* g, short* l){
  __builtin_amdgcn_global_load_lds((const __attribute__((address_space(1))) void*)g,
                                   (__attribute__((address_space(3))) void*)l, 16, 0, 0);
}

// ---- fused preprocessing: cast u | transpose W_in | transpose W_out | zero out ----
// grid: [0,1024) cast, [1024,2144) W_in 140x8, [2144,2656) W_out 32x16, [2656,3680) zero
__global__ __launch_bounds__(256) void prep_inputs(const float* __restrict__ u, short* __restrict__ u16,
                                                   const float* __restrict__ W_in, short* __restrict__ WtIn,
                                                   const float* __restrict__ W_out, short* __restrict__ WtOut,
                                                   float* __restrict__ outz){
  int b = blockIdx.x;
  int tid = threadIdx.x;
  if (b < 1024){
    int i = (b * 256 + tid) * 4;
    f4 v = *(const f4*)(u + i);
    uint2 pk; pk.x = pack2(v.x, v.y); pk.y = pack2(v.z, v.w);
    *(uint2*)(u16 + i) = pk;
    return;
  }
  if (b >= 2656){
    int i = ((b - 2656) * 256 + tid) * 4;
    *(f4*)(outz + i) = (f4){0.f, 0.f, 0.f, 0.f};
    return;
  }
  const float* in; short* outp; int R, lda, bx, by;
  if (b < 2144){ int idx = b - 1024; bx = idx % 140; by = idx / 140; in = W_in;  outp = WtIn;  R = 1024; lda = 4480; }
  else         { int idx = b - 2144; bx = idx & 31;  by = idx >> 5;  in = W_out; outp = WtOut; R = 2048; lda = 1024; }
  __shared__ float tile[32][132];
  int bc = bx * 32, br = by * 128;
  int c = tid & 31, r0 = tid >> 5;
  #pragma unroll
  for (int i = 0; i < 16; i++){
    int r = r0 + i * 8;
    tile[c][r] = in[(size_t)(br + r) * lda + bc + c];
  }
  __syncthreads();
  #pragma unroll
  for (int i = 0; i < 4; i++){
    int task = tid + 256 * i;
    int cc = task >> 5;
    int rg = (task & 31) * 4;
    f4 v = *(const f4*)&tile[cc][rg];
    uint2 pk; pk.x = pack2(v.x, v.y); pk.y = pack2(v.z, v.w);
    *(uint2*)(outp + (size_t)(bc + cc) * R + br + rg) = pk;
  }
}

// ---- GEMM1: u16 @ WtInᵀ; 128x64 tile, 8 waves (512 thr), BK=64, ring-3 + counted vmcnt,
//      560 blocks (72KB LDS -> 2 blocks/CU = 4 waves/SIMD). Octet swizzle src+read. ----
__global__ __launch_bounds__(512) void gemm1_kernel(const short* __restrict__ A, const short* __restrict__ Bt,
                                                    short* __restrict__ zx, short* __restrict__ xTb,
                                                    float* __restrict__ projT){
  const int K = 1024;
  __shared__ __align__(16) short As[3][128 * 64];
  __shared__ __align__(16) short Bs[3][64 * 64];
  const int tid  = threadIdx.x;
  const int wave = tid >> 6;
  const int lane = tid & 63;
  // 560 = 8 XCDs x 70, m fast within chunk (B n-panel XCD-local, ~1.1MB/XCD)
  int wg = (blockIdx.x & 7) * 70 + (blockIdx.x >> 3);
  const int m0 = (wg & 7) * 128;
  const int n0 = (wg >> 3) * 64;
  const int wm = (wave >> 1) * 32;          // {0,32,64,96}
  const int wn = (wave & 1) * 32;           // {0,32}
  const int quad = lane >> 4;
  const int r16  = lane & 15;
  const int rsw  = r16 & 7;

  f4 acc[2][2];
  #pragma unroll
  for (int i = 0; i < 2; i++)
    #pragma unroll
    for (int j = 0; j < 2; j++) acc[i][j] = (f4){0.f, 0.f, 0.f, 0.f};

  const int srow = tid >> 3;                // 0..63
  const int soct = tid & 7;
  const int og   = (soct ^ (srow & 7)) * 8; // swizzled source octet ((srow+64)&7 == srow&7)
  const short* gA0 = A  + (size_t)(m0 + srow) * K + og;
  const short* gB0 = Bt + (size_t)(n0 + srow) * K + og;

  // 3 loads/thread/step, uniform across all 8 waves (vmcnt counting relies on this)
#define G1_STAGE(buf, kt) do {                                             \
    const int ko_ = (kt) * 64;                                             \
    gload_lds16(gA0 + ko_,                  &As[buf][tid * 8]);            \
    gload_lds16(gA0 + (size_t)64 * K + ko_, &As[buf][(tid + 512) * 8]);    \
    gload_lds16(gB0 + ko_,                  &Bs[buf][tid * 8]);            \
  } while(0)

  G1_STAGE(0, 0);
  G1_STAGE(1, 1);

  for (int kt = 0; kt < 16; ++kt){
    if (kt < 15) asm volatile("s_waitcnt vmcnt(3)" ::: "memory");
    else         asm volatile("s_waitcnt vmcnt(0)" ::: "memory");
    __builtin_amdgcn_s_barrier();
    __builtin_amdgcn_sched_barrier(0);
    if (kt + 2 < 16){
      int nb = kt + 2 - ((kt + 2) / 3) * 3;
      G1_STAGE(nb, kt + 2);
    }
    const short* Ac = As[kt % 3];
    const short* Bc = Bs[kt % 3];
    #pragma unroll
    for (int ks = 0; ks < 2; ++ks){
      const int oq = ((ks * 4 + quad) ^ rsw) * 8;
      short8 af[2], bf[2];
      #pragma unroll
      for (int i = 0; i < 2; i++)
        af[i] = *(const short8*)&Ac[(wm + i * 16 + r16) * 64 + oq];
      #pragma unroll
      for (int j = 0; j < 2; j++)
        bf[j] = *(const short8*)&Bc[(wn + j * 16 + r16) * 64 + oq];
      #pragma unroll
      for (int i = 0; i < 2; i++)
        #pragma unroll
        for (int j = 0; j < 2; j++)
          acc[i][j] = __builtin_amdgcn_mfma_f32_16x16x32_bf16(af[i], bf[j], acc[i][j], 0, 0, 0);
    }
  }
#undef G1_STAGE

  // epilogue: col-group (16 wide) is wave-uniform; boundaries 2048/4096 are multiples of 16
  #pragma unroll
  for (int i = 0; i < 2; i++)
    #pragma unroll
    for (int j = 0; j < 2; j++){
      int colb = n0 + wn + j * 16 + r16;
      int rowb = m0 + wm + i * 16 + quad * 4;
      if (colb < 2048){                    // z -> bf16
        #pragma unroll
        for (int rr = 0; rr < 4; ++rr)
          zx[(size_t)(rowb + rr) * 4096 + colb] = f2b(acc[i][j][rr]);
      } else if (colb < 4096){             // x -> bf16 + transposed bf16
        uint2 pk; pk.x = pack2(acc[i][j][0], acc[i][j][1]); pk.y = pack2(acc[i][j][2], acc[i][j][3]);
        *(uint2*)(xTb + (size_t)(colb - 2048) * 1024 + rowb) = pk;
        #pragma unroll
        for (int rr = 0; rr < 4; ++rr)
          zx[(size_t)(rowb + rr) * 4096 + colb] = f2b(acc[i][j][rr]);
      } else {                             // tail -> fp32
        #pragma unroll
        for (int rr = 0; rr < 4; ++rr)
          projT[(size_t)(rowb + rr) * 384 + (colb - 4096)] = acc[i][j][rr];
      }
    }
}

// ---- GEMM2: out += yb16 @ WtOutᵀ; 128x64 tile, 8 waves, BK=64, splitK=4, ring-3, 512 blocks ----
__global__ __launch_bounds__(512) void gemm2_kernel(const short* __restrict__ A, const short* __restrict__ Bt,
                                                    float* __restrict__ C){
  const int N = 1024, K = 2048;
  __shared__ __align__(16) short As[3][128 * 64];
  __shared__ __align__(16) short Bs[3][64 * 64];
  const int tid  = threadIdx.x;
  const int wave = tid >> 6;
  const int lane = tid & 63;
  // 512 = 8 x 64 chunked swizzle; m fast
  int wg = (blockIdx.x & 7) * 64 + (blockIdx.x >> 3);
  const int m0 = (wg & 7) * 128;
  const int n0 = ((wg >> 3) & 15) * 64;
  const int k0 = (wg >> 7) * 512;
  const int wm = (wave >> 1) * 32;
  const int wn = (wave & 1) * 32;
  const int quad = lane >> 4;
  const int r16  = lane & 15;
  const int rsw  = r16 & 7;

  f4 acc[2][2];
  #pragma unroll
  for (int i = 0; i < 2; i++)
    #pragma unroll
    for (int j = 0; j < 2; j++) acc[i][j] = (f4){0.f, 0.f, 0.f, 0.f};

  const int srow = tid >> 3;
  const int soct = tid & 7;
  const int og   = (soct ^ (srow & 7)) * 8;
  const short* gA0 = A  + (size_t)(m0 + srow) * K + k0 + og;
  const short* gB0 = Bt + (size_t)(n0 + srow) * K + k0 + og;

#define G2_STAGE(buf, kt) do {                                             \
    const int ko_ = (kt) * 64;                                             \
    gload_lds16(gA0 + ko_,                  &As[buf][tid * 8]);            \
    gload_lds16(gA0 + (size_t)64 * K + ko_, &As[buf][(tid + 512) * 8]);    \
    gload_lds16(gB0 + ko_,                  &Bs[buf][tid * 8]);            \
  } while(0)

  G2_STAGE(0, 0);
  G2_STAGE(1, 1);

  for (int kt = 0; kt < 8; ++kt){
    if (kt < 7) asm volatile("s_waitcnt vmcnt(3)" ::: "memory");
    else        asm volatile("s_waitcnt vmcnt(0)" ::: "memory");
    __builtin_amdgcn_s_barrier();
    __builtin_amdgcn_sched_barrier(0);
    if (kt + 2 < 8){
      int nb = kt + 2 - ((kt + 2) / 3) * 3;
      G2_STAGE(nb, kt + 2);
    }
    const short* Ac = As[kt % 3];
    const short* Bc = Bs[kt % 3];
    #pragma unroll
    for (int ks = 0; ks < 2; ++ks){
      const int oq = ((ks * 4 + quad) ^ rsw) * 8;
      short8 af[2], bf[2];
      #pragma unroll
      for (int i = 0; i < 2; i++)
        af[i] = *(const short8*)&Ac[(wm + i * 16 + r16) * 64 + oq];
      #pragma unroll
      for (int j = 0; j < 2; j++)
        bf[j] = *(const short8*)&Bc[(wn + j * 16 + r16) * 64 + oq];
      #pragma unroll
      for (int i = 0; i < 2; i++)
        #pragma unroll
        for (int j = 0; j < 2; j++)
          acc[i][j] = __builtin_amdgcn_mfma_f32_16x16x32_bf16(af[i], bf[j], acc[i][j], 0, 0, 0);
    }
  }
#undef G2_STAGE

  #pragma unroll
  for (int i = 0; i < 2; i++)
    #pragma unroll
    for (int j = 0; j < 2; j++)
      #pragma unroll
      for (int rr = 0; rr < 4; ++rr){
        int row = m0 + wm + i * 16 + quad * 4 + rr;
        int col = n0 + wn + j * 16 + r16;
        unsafeAtomicAdd(&C[(size_t)row * N + col], acc[i][j][rr]);
      }
}

// ---- fused: [0,32) per-head prefix scan (Lcum/u2b/c1b) | [32,1056) theta cumsum+sincos ----
__global__ __launch_bounds__(256) void scan_theta(const float* __restrict__ projT,
                                                  const float* __restrict__ dt_bias,
                                                  float* __restrict__ Lcum, float* __restrict__ u2b,
                                                  float* __restrict__ c1b,
                                                  float* __restrict__ cosb, float* __restrict__ sinb){
  int b = blockIdx.x;
  int tid = threadIdx.x;
  int t0 = tid * 4;
  int lane = tid & 63, wave = tid >> 6;
  __shared__ float wsum[4];
  if (b < 32){
    int h = b;
    float dtbias = dt_bias[h];
    float dt5[5], lam5[5];
    #pragma unroll
    for (int i = 0; i < 5; i++){
      int t = t0 + i;
      if (t < 1024){
        const float* row = projT + (size_t)t * 384;
        dt5[i]  = softplus_f(row[256 + h] + dtbias);
        lam5[i] = 1.f / (1.f + __expf(-row[320 + h]));
      } else { dt5[i] = 0.f; lam5[i] = 0.f; }
    }
    float v[4], c1[4], c2n[4];
    #pragma unroll
    for (int i = 0; i < 4; i++){
      int t = t0 + i;
      const float* row = projT + (size_t)t * 384;
      float Ah = -fmaxf(softplus_f(row[288 + h]), 1e-4f);
      v[i]   = Ah * dt5[i];
      c1[i]  = dt5[i] * lam5[i];
      c2n[i] = dt5[i + 1] * (1.f - lam5[i + 1]);
    }
    v[1] += v[0]; v[2] += v[1]; v[3] += v[2];
    float tot = v[3], sc = tot;
    #pragma unroll
    for (int off = 1; off < 64; off <<= 1){
      float n = __shfl_up(sc, off, 64);
      if (lane >= off) sc += n;
    }
    if (lane == 63) wsum[wave] = sc;
    __syncthreads();
    float base = sc - tot;
    for (int w = 0; w < wave; ++w) base += wsum[w];
    #pragma unroll
    for (int i = 0; i < 4; i++){
      int t = t0 + i;
      Lcum[h * 1024 + t] = base + v[i];
      u2b[h * 1024 + t]  = c1[i] + c2n[i];
      c1b[h * 1024 + t]  = c1[i];
    }
  } else {
    int hk = b - 32;
    int h = hk >> 5, k = hk & 31;
    float dtbias = dt_bias[h];
    float v[4];
    #pragma unroll
    for (int i = 0; i < 4; i++){
      const float* row = projT + (size_t)(t0 + i) * 384;
      float dt = softplus_f(row[256 + h] + dtbias);
      v[i] = row[352 + k] * dt;
    }
    v[1] += v[0]; v[2] += v[1]; v[3] += v[2];
    float tot = v[3], sc = tot;
    #pragma unroll
    for (int off = 1; off < 64; off <<= 1){
      float n = __shfl_up(sc, off, 64);
      if (lane >= off) sc += n;
    }
    if (lane == 63) wsum[wave] = sc;
    __syncthreads();
    float base = sc - tot;
    for (int w = 0; w < wave; ++w) base += wsum[w];
    #pragma unroll
    for (int i = 0; i < 4; i++){
      float th = base + v[i];
      float s, c;
      __sincosf(th, &s, &c);
      int t = t0 + i;
      cosb[(size_t)t * 1024 + h * 32 + k] = c;
      sinb[(size_t)t * 1024 + h * 32 + k] = s;
    }
  }
}

// ---- rmsnorm+bias+rope -> Bb/Cb ----
__global__ __launch_bounds__(256) void bcxt_kernel(const float* __restrict__ projT,
                                                   const float* __restrict__ B_bias, const float* __restrict__ C_bias,
                                                   const float* __restrict__ Bn_w, const float* __restrict__ Cn_w,
                                                   const float* __restrict__ cosb, const float* __restrict__ sinb,
                                                   short* __restrict__ Bb, short* __restrict__ Cb){
  int t = blockIdx.x;
  int tid = threadIdx.x;
  __shared__ float vv[2][128];
  __shared__ float red[4];
  int n = tid & 127;
  int isC = tid >> 7;
  float val = projT[(size_t)t * 384 + isC * 128 + n];
  float ss = val * val;
  #pragma unroll
  for (int off = 32; off >= 1; off >>= 1) ss += __shfl_down(ss, off);
  int wave = tid >> 6, lane = tid & 63;
  if (lane == 0) red[wave] = ss;
  __syncthreads();
  float rsv = isC ? rsqrtf((red[2] + red[3]) * (1.f / 128.f) + 1e-5f)
                  : rsqrtf((red[0] + red[1]) * (1.f / 128.f) + 1e-5f);
  vv[isC][n] = val * rsv * (isC ? Cn_w[n] : Bn_w[n]);
  __syncthreads();
  const float* cb = cosb + (size_t)t * 1024;
  const float* sb = sinb + (size_t)t * 1024;
  #pragma unroll
  for (int it = 0; it < 8; it++){
    int task = tid + 256 * it;
    int arr  = task >> 10;
    int rem  = task & 1023;
    int h    = rem >> 5;
    int n0   = (rem & 31) * 4;
    const float* bias = arr ? C_bias : B_bias;
    const float* base = vv[arr];
    f4 bv = *(const f4*)&base[n0];
    f4 bi = *(const f4*)&bias[h * 128 + n0];
    f4 o;
    if (n0 < 32){
      f4 bv2 = *(const f4*)&base[n0 + 32];
      f4 bi2 = *(const f4*)&bias[h * 128 + n0 + 32];
      f4 cv = *(const f4*)&cb[h * 32 + n0];
      f4 sv = *(const f4*)&sb[h * 32 + n0];
      #pragma unroll
      for (int q = 0; q < 4; q++) o[q] = (bv[q] + bi[q]) * cv[q] - (bv2[q] + bi2[q]) * sv[q];
    } else if (n0 < 64){
      int k0 = n0 - 32;
      f4 bv1 = *(const f4*)&base[k0];
      f4 bi1 = *(const f4*)&bias[h * 128 + k0];
      f4 cv = *(const f4*)&cb[h * 32 + k0];
      f4 sv = *(const f4*)&sb[h * 32 + k0];
      #pragma unroll
      for (int q = 0; q < 4; q++) o[q] = (bv1[q] + bi1[q]) * sv[q] + (bv[q] + bi[q]) * cv[q];
    } else {
      #pragma unroll
      for (int q = 0; q < 4; q++) o[q] = bv[q] + bi[q];
    }
    uint2 pk; pk.x = pack2(o.x, o.y); pk.y = pack2(o.z, o.w);
    short* outp = arr ? Cb : Bb;
    *(uint2*)(outp + (size_t)t * 4096 + h * 128 + n0) = pk;
  }
}

// ---- per-chunk state contribution, split n-halves: 512 blocks (2/CU) ----
__global__ __launch_bounds__(256) void hpart_kernel(const short* __restrict__ xTb, const short* __restrict__ Bb,
                                                    const float* __restrict__ Lcum, const float* __restrict__ u2b,
                                                    short* __restrict__ Hpart){
  int h = blockIdx.x >> 4, c = (blockIdx.x >> 1) & 7, nh = blockIdx.x & 1;
  int t0 = c * 128;
  int tid = threadIdx.x;
  __shared__ float wS[128];
  if (tid < 128){
    float Lend = Lcum[h * 1024 + t0 + 127];
    wS[tid] = __expf(Lend - Lcum[h * 1024 + t0 + tid]) * u2b[h * 1024 + t0 + tid];
  }
  __syncthreads();
  int wave = tid >> 6, lane = tid & 63, quad = lane >> 4, r16 = lane & 15;
  int n0 = nh * 64 + wave * 16;
  f4 acc[4];
  #pragma unroll
  for (int i = 0; i < 4; i++) acc[i] = (f4){0.f, 0.f, 0.f, 0.f};

  const ushort* Bh = (const ushort*)Bb + (size_t)t0 * 4096 + h * 128;
  #pragma unroll
  for (int kk = 0; kk < 4; ++kk){
    int sb = kk * 32 + quad * 8;
    short8 af[4];
    #pragma unroll
    for (int i = 0; i < 4; i++){
      int p = i * 16 + r16;
      af[i] = *(const short8*)(xTb + (size_t)(h * 64 + p) * 1024 + t0 + sb);
    }
    float wv[8];
    #pragma unroll
    for (int jj = 0; jj < 8; jj++) wv[jj] = wS[sb + jj];
    int nn = n0 + r16;
    float e[8];
    #pragma unroll
    for (int jj = 0; jj < 8; jj++)
      e[jj] = b2f(Bh[(size_t)(sb + jj) * 4096 + nn]) * wv[jj];
    union { short8 s; uint32_t u[4]; } fr;
    #pragma unroll
    for (int q = 0; q < 4; q++) fr.u[q] = pack2(e[2 * q], e[2 * q + 1]);
    short8 bfr = fr.s;
    #pragma unroll
    for (int i = 0; i < 4; i++)
      acc[i] = __builtin_amdgcn_mfma_f32_16x16x32_bf16(af[i], bfr, acc[i], 0, 0, 0);
  }

  short* out = Hpart + ((size_t)(h * 8 + c)) * 8192;
  int nn = n0 + r16;
  #pragma unroll
  for (int i = 0; i < 4; i++)
    #pragma unroll
    for (int rr = 0; rr < 4; ++rr){
      int p = i * 16 + quad * 4 + rr;
      out[p * 128 + nn] = f2b(acc[i][rr]);
    }
}

// ---- chunked dual + fused hscan, split trow-halves: 512 blocks (~36KB LDS, 2/CU) ----
#define GS 144
__global__ __launch_bounds__(256) void chunky_kernel(const short* __restrict__ Cb, const short* __restrict__ Bbg,
                                                     const short* __restrict__ xTb, const short* __restrict__ Hpart,
                                                     const float* __restrict__ Lcum, const float* __restrict__ u2b,
                                                     const float* __restrict__ c1b,
                                                     const short* __restrict__ zx, const float* __restrict__ D_par,
                                                     short* __restrict__ yb16){
  int h = blockIdx.x >> 4, c = (blockIdx.x >> 1) & 7, half = blockIdx.x & 1;
  int t0 = c * 128;
  int tb = half * 64;                              // trow base within chunk
  __shared__ __align__(16) short Gt[64 * GS];
  __shared__ __align__(16) short Hu[64 * 128];     // XOR-swizzled: byte ^= (row&7)<<4
  __shared__ float Lc[128], u2v[128], c1v[128];
  int tid = threadIdx.x;
  if (tid < 128){
    Lc[tid]  = Lcum[h * 1024 + t0 + tid];
    u2v[tid] = u2b[h * 1024 + t0 + tid];
    c1v[tid] = c1b[h * 1024 + t0 + tid];
  }
  float Lprev = (c > 0) ? Lcum[h * 1024 + t0 - 1] : 0.f;
  float Dp = D_par[h];

  // ---- fused hscan: decay-sum of previous chunks into Hu (redundant per half, cheap) ----
  {
    float hacc[32];
    #pragma unroll
    for (int q = 0; q < 32; q++) hacc[q] = 0.f;
    for (int cp = 0; cp < c; ++cp){
      float dec = __expf(Lprev - Lcum[h * 1024 + cp * 128 + 127]);
      const short8* hp = (const short8*)((const ushort*)Hpart + ((size_t)(h * 8 + cp)) * 8192 + tid * 32);
      #pragma unroll
      for (int q = 0; q < 4; q++){
        short8 v = hp[q];
        #pragma unroll
        for (int e = 0; e < 8; e++) hacc[q * 8 + e] += dec * b2f((uint16_t)v[e]);
      }
    }
    int p = tid >> 2;                                // row (0..63), constant per thread
    int wbase = tid * 64;                            // byte base in Hu
    #pragma unroll
    for (int q = 0; q < 4; q++){
      union { short8 s; uint32_t u[4]; } fr;
      #pragma unroll
      for (int p2 = 0; p2 < 4; p2++) fr.u[p2] = pack2(hacc[q * 8 + p2 * 2], hacc[q * 8 + p2 * 2 + 1]);
      int off = (wbase + q * 16) ^ ((p & 7) << 4);
      *(short8*)((char*)Hu + off) = fr.s;
    }
  }

  int wave = tid >> 6, lane = tid & 63, quad = lane >> 4, r16 = lane & 15;
  // S phase: 64 trows x 128 scols, waves 2x2: wm2 in {0,32}, wn2 in {0,64}
  int wm2 = (wave >> 1) * 32, wn2 = (wave & 1) * 64;

  f4 acc[2][4];
  #pragma unroll
  for (int i = 0; i < 2; i++)
    #pragma unroll
    for (int j = 0; j < 4; j++) acc[i][j] = (f4){0.f, 0.f, 0.f, 0.f};
  #pragma unroll
  for (int kk = 0; kk < 4; ++kk){
    short8 af[2], bf[4];
    #pragma unroll
    for (int i = 0; i < 2; i++)
      af[i] = *(const short8*)(Cb + (size_t)(t0 + tb + wm2 + i * 16 + r16) * 4096 + h * 128 + kk * 32 + quad * 8);
    #pragma unroll
    for (int j = 0; j < 4; j++)
      bf[j] = *(const short8*)(Bbg + (size_t)(t0 + wn2 + j * 16 + r16) * 4096 + h * 128 + kk * 32 + quad * 8);
    #pragma unroll
    for (int i = 0; i < 2; i++)
      #pragma unroll
      for (int j = 0; j < 4; j++)
        acc[i][j] = __builtin_amdgcn_mfma_f32_16x16x32_bf16(af[i], bf[j], acc[i][j], 0, 0, 0);
  }
  __syncthreads();   // covers Lc/u2v/c1v and Hu writes

  #pragma unroll
  for (int i = 0; i < 2; i++){
    #pragma unroll
    for (int rr = 0; rr < 4; ++rr){
      int tl = wm2 + i * 16 + quad * 4 + rr;       // local trow 0..63
      int trow = tb + tl;
      float Lt = Lc[trow];
      #pragma unroll
      for (int j = 0; j < 4; j++){
        int scol = wn2 + j * 16 + r16;
        float g = 0.f;
        if (scol <= trow){
          float wcoef = (scol == trow) ? c1v[scol] : u2v[scol];
          g = acc[i][j][rr] * wcoef * __expf(Lt - Lc[scol]);
        }
        Gt[tl * GS + scol] = f2b(g);
      }
    }
  }
  __syncthreads();

  // Y phase: each wave owns 16 trows
  f4 accY[4], accZ[4];
  #pragma unroll
  for (int j = 0; j < 4; j++){ accY[j] = (f4){0.f,0.f,0.f,0.f}; accZ[j] = (f4){0.f,0.f,0.f,0.f}; }
  int m0 = wave * 16;
  #pragma unroll
  for (int kk = 0; kk < 4; ++kk){
    short8 ag, ac, bx[4], bh[4];
    ag = *(const short8*)&Gt[(m0 + r16) * GS + kk * 32 + quad * 8];
    ac = *(const short8*)(Cb + (size_t)(t0 + tb + m0 + r16) * 4096 + h * 128 + kk * 32 + quad * 8);
    #pragma unroll
    for (int j = 0; j < 4; j++){
      bx[j] = *(const short8*)(xTb + (size_t)(h * 64 + j * 16 + r16) * 1024 + t0 + kk * 32 + quad * 8);
      int hrow = j * 16 + r16;
      int hoff = (hrow * 256 + kk * 64 + quad * 16) ^ ((hrow & 7) << 4);
      bh[j] = *(const short8*)((const char*)Hu + hoff);
    }
    #pragma unroll
    for (int j = 0; j < 4; j++){
      accY[j] = __builtin_amdgcn_mfma_f32_16x16x32_bf16(ag, bx[j], accY[j], 0, 0, 0);
      accZ[j] = __builtin_amdgcn_mfma_f32_16x16x32_bf16(ac, bh[j], accZ[j], 0, 0, 0);
    }
  }
  // fused post: y = (y + D*x) * silu(z), cast bf16
  const ushort* zxu = (const ushort*)zx;
  #pragma unroll
  for (int rr = 0; rr < 4; ++rr){
    int tl = m0 + quad * 4 + rr;
    int trow = tb + tl;
    float ei = __expf(Lc[trow] - Lprev);
    const ushort* zrow = zxu + (size_t)(t0 + trow) * 4096;
    #pragma unroll
    for (int j = 0; j < 4; j++){
      int col = h * 64 + j * 16 + r16;
      float zv = b2f(zrow[col]);
      float xv = b2f(zrow[2048 + col]);
      float yv = accY[j][rr] + ei * accZ[j][rr] + Dp * xv;
      float o = yv * (zv / (1.f + __expf(-zv)));
      yb16[(size_t)(t0 + trow) * 2048 + col] = f2b(o);
    }
  }
}

extern "C" void kernel_launch(void* const* d_in, const int* in_sizes, int n_in,
                              void* d_out, int out_size, void* d_ws, size_t ws_size,
                              hipStream_t stream){
  const float* u       = (const float*)d_in[0];
  const float* W_in    = (const float*)d_in[1];
  const float* dt_bias = (const float*)d_in[2];
  const float* B_bias  = (const float*)d_in[3];
  const float* C_bias  = (const float*)d_in[4];
  const float* Bn_w    = (const float*)d_in[5];
  const float* Cn_w    = (const float*)d_in[6];
  const float* D_par   = (const float*)d_in[7];
  const float* W_out   = (const float*)d_in[8];
  float* out = (float*)d_out;

  char* ws = (char*)d_ws;
  short* u16   = (short*)(ws + 0);          // 2,097,152
  short* WtIn  = (short*)(ws + 2097152);    // 9,175,040
  short* WtOut = (short*)(ws + 11272192);   // 4,194,304
  short* zx    = (short*)(ws + 15466496);   // 8,388,608
  float* projT = (float*)(ws + 23855104);   // 1,572,864
  float* cosb  = (float*)(ws + 25427968);   // 4,194,304
  float* sinb  = (float*)(ws + 29622272);   // 4,194,304
  short* Bb    = (short*)(ws + 33816576);   // 8,388,608
  short* Cb    = (short*)(ws + 42205184);   // 8,388,608
  short* xTb   = (short*)(ws + 50593792);   // 4,194,304
  float* Lcum  = (float*)(ws + 54788096);   // 131,072
  float* u2b   = (float*)(ws + 54919168);   // 131,072
  float* c1b   = (float*)(ws + 55050240);   // 131,072
  short* Hpart = (short*)(ws + 55181312);   // 4,194,304
  short* yb16  = (short*)(ws + 59375616);   // 4,194,304 -> total 63,569,920 B

  prep_inputs<<<3680, 256, 0, stream>>>(u, u16, W_in, WtIn, W_out, WtOut, out);
  gemm1_kernel<<<560, 512, 0, stream>>>(u16, WtIn, zx, xTb, projT);
  scan_theta<<<1056, 256, 0, stream>>>(projT, dt_bias, Lcum, u2b, c1b, cosb, sinb);
  bcxt_kernel<<<1024, 256, 0, stream>>>(projT, B_bias, C_bias, Bn_w, Cn_w, cosb, sinb, Bb, Cb);
  hpart_kernel<<<512, 256, 0, stream>>>(xTb, Bb, Lcum, u2b, Hpart);
  chunky_kernel<<<512, 256, 0, stream>>>(Cb, Bb, xTb, Hpart, Lcum, u2b, c1b, zx, D_par, yb16);
  gemm2_kernel<<<512, 512, 0, stream>>>(yb16, WtOut, out);
}

// Round 11
// 192.100 us; speedup vs baseline: 1.0253x; 1.0253x over previous
//
#include <hip/hip_runtime.h>
#include <stdint.h>

#define SEQ     1024
// projT tail columns (fp32): Bp=0, Cp=128, dd_dt=256, dd_A=288, trap=320, ang=352  (width 384)

typedef __attribute__((ext_vector_type(8))) short short8;
typedef __attribute__((ext_vector_type(4))) float f4;

__device__ __forceinline__ short f2b(float f){
  union { float f; uint32_t u; } v; v.f = f;
  uint32_t r = (v.u + 0x7fffu + ((v.u >> 16) & 1u)) >> 16;
  return (short)(uint16_t)r;
}
__device__ __forceinline__ float b2f(uint16_t u){
  union { uint32_t u; float f; } v; v.u = ((uint32_t)u) << 16; return v.f;
}
__device__ __forceinline__ uint32_t pack2(float lo, float hi){
  return (uint32_t)(uint16_t)f2b(lo) | ((uint32_t)(uint16_t)f2b(hi) << 16);
}
__device__ __forceinline__ float softplus_f(float x){
  return x > 20.f ? x : log1pf(__expf(x));
}
// async global->LDS 16B/lane; lds dest must be wave-uniform base + lane*16 order
__device__ __forceinline__ void gload_lds16(const short* g, short* l){
  __builtin_amdgcn_global_load_lds((const __attribute__((address_space(1))) void*)g,
                                   (__attribute__((address_space(3))) void*)l, 16, 0, 0);
}

// ---- fused preprocessing: cast u | transpose W_in | transpose W_out | zero out ----
// grid: [0,1024) cast, [1024,2144) W_in 140x8, [2144,2656) W_out 32x16, [2656,3680) zero
__global__ __launch_bounds__(256) void prep_inputs(const float* __restrict__ u, short* __restrict__ u16,
                                                   const float* __restrict__ W_in, short* __restrict__ WtIn,
                                                   const float* __restrict__ W_out, short* __restrict__ WtOut,
                                                   float* __restrict__ outz){
  int b = blockIdx.x;
  int tid = threadIdx.x;
  if (b < 1024){
    int i = (b * 256 + tid) * 4;
    f4 v = *(const f4*)(u + i);
    uint2 pk; pk.x = pack2(v.x, v.y); pk.y = pack2(v.z, v.w);
    *(uint2*)(u16 + i) = pk;
    return;
  }
  if (b >= 2656){
    int i = ((b - 2656) * 256 + tid) * 4;
    *(f4*)(outz + i) = (f4){0.f, 0.f, 0.f, 0.f};
    return;
  }
  const float* in; short* outp; int R, lda, bx, by;
  if (b < 2144){ int idx = b - 1024; bx = idx % 140; by = idx / 140; in = W_in;  outp = WtIn;  R = 1024; lda = 4480; }
  else         { int idx = b - 2144; bx = idx & 31;  by = idx >> 5;  in = W_out; outp = WtOut; R = 2048; lda = 1024; }
  __shared__ float tile[32][132];
  int bc = bx * 32, br = by * 128;
  int c = tid & 31, r0 = tid >> 5;
  #pragma unroll
  for (int i = 0; i < 16; i++){
    int r = r0 + i * 8;
    tile[c][r] = in[(size_t)(br + r) * lda + bc + c];
  }
  __syncthreads();
  #pragma unroll
  for (int i = 0; i < 4; i++){
    int task = tid + 256 * i;
    int cc = task >> 5;
    int rg = (task & 31) * 4;
    f4 v = *(const f4*)&tile[cc][rg];
    uint2 pk; pk.x = pack2(v.x, v.y); pk.y = pack2(v.z, v.w);
    *(uint2*)(outp + (size_t)(bc + cc) * R + br + rg) = pk;
  }
}

// ---- GEMM1: u16 @ WtInᵀ; 64x64 tile, BK=64, ring-3 LDS + counted vmcnt (T4), 1120 blocks
//      (48KB LDS -> 3 blocks/CU = 3 waves/SIMD). Octet swizzle on source+read, LDS linear. ----
__global__ __launch_bounds__(256) void gemm1_kernel(const short* __restrict__ A, const short* __restrict__ Bt,
                                                    short* __restrict__ zx, short* __restrict__ xTb,
                                                    float* __restrict__ projT){
  const int K = 1024;
  __shared__ __align__(16) short As[3][64 * 64];
  __shared__ __align__(16) short Bs[3][64 * 64];
  const int tid  = threadIdx.x;
  const int wave = tid >> 6;
  const int lane = tid & 63;
  // 1120 = 8 XCDs x 140, m fast within chunk (B n-panel XCD-local)
  int wg = (blockIdx.x & 7) * 140 + (blockIdx.x >> 3);
  const int m0 = (wg & 15) * 64;
  const int n0 = (wg >> 4) * 64;
  const int wm = (wave >> 1) * 32;
  const int wn = (wave & 1) * 32;
  const int quad = lane >> 4;
  const int r16  = lane & 15;
  const int rsw  = r16 & 7;

  f4 acc[2][2];
  #pragma unroll
  for (int i = 0; i < 2; i++)
    #pragma unroll
    for (int j = 0; j < 2; j++) acc[i][j] = (f4){0.f, 0.f, 0.f, 0.f};

  const int srow = tid >> 3;                // 0..31
  const int soct = tid & 7;
  const int og   = (soct ^ (srow & 7)) * 8; // swizzled source octet ((srow+32)&7 == srow&7)
  const short* gA0 = A  + (size_t)(m0 + srow) * K + og;
  const short* gB0 = Bt + (size_t)(n0 + srow) * K + og;

  // 4 loads/thread/step, uniform across waves (vmcnt counting relies on this)
#define G1_STAGE(buf, kt) do {                                             \
    const int ko_ = (kt) * 64;                                             \
    gload_lds16(gA0 + ko_,                  &As[buf][tid * 8]);            \
    gload_lds16(gA0 + (size_t)32 * K + ko_, &As[buf][(tid + 256) * 8]);    \
    gload_lds16(gB0 + ko_,                  &Bs[buf][tid * 8]);            \
    gload_lds16(gB0 + (size_t)32 * K + ko_, &Bs[buf][(tid + 256) * 8]);    \
  } while(0)

  G1_STAGE(0, 0);
  G1_STAGE(1, 1);

  for (int kt = 0; kt < 16; ++kt){
    if (kt < 15) asm volatile("s_waitcnt vmcnt(4)" ::: "memory");
    else         asm volatile("s_waitcnt vmcnt(0)" ::: "memory");
    __builtin_amdgcn_s_barrier();
    __builtin_amdgcn_sched_barrier(0);
    if (kt + 2 < 16){
      int nb = kt + 2 - ((kt + 2) / 3) * 3;
      G1_STAGE(nb, kt + 2);
    }
    const short* Ac = As[kt % 3];
    const short* Bc = Bs[kt % 3];
    #pragma unroll
    for (int ks = 0; ks < 2; ++ks){
      const int oq = ((ks * 4 + quad) ^ rsw) * 8;
      short8 af[2], bf[2];
      #pragma unroll
      for (int i = 0; i < 2; i++)
        af[i] = *(const short8*)&Ac[(wm + i * 16 + r16) * 64 + oq];
      #pragma unroll
      for (int j = 0; j < 2; j++)
        bf[j] = *(const short8*)&Bc[(wn + j * 16 + r16) * 64 + oq];
      #pragma unroll
      for (int i = 0; i < 2; i++)
        #pragma unroll
        for (int j = 0; j < 2; j++)
          acc[i][j] = __builtin_amdgcn_mfma_f32_16x16x32_bf16(af[i], bf[j], acc[i][j], 0, 0, 0);
    }
  }
#undef G1_STAGE

  // epilogue: col-group (16 wide) is wave-uniform; boundaries 2048/4096 are multiples of 16
  #pragma unroll
  for (int i = 0; i < 2; i++)
    #pragma unroll
    for (int j = 0; j < 2; j++){
      int colb = n0 + wn + j * 16 + r16;
      int rowb = m0 + wm + i * 16 + quad * 4;
      if (colb < 2048){                    // z -> bf16
        #pragma unroll
        for (int rr = 0; rr < 4; ++rr)
          zx[(size_t)(rowb + rr) * 4096 + colb] = f2b(acc[i][j][rr]);
      } else if (colb < 4096){             // x -> bf16 + transposed bf16
        uint2 pk; pk.x = pack2(acc[i][j][0], acc[i][j][1]); pk.y = pack2(acc[i][j][2], acc[i][j][3]);
        *(uint2*)(xTb + (size_t)(colb - 2048) * 1024 + rowb) = pk;
        #pragma unroll
        for (int rr = 0; rr < 4; ++rr)
          zx[(size_t)(rowb + rr) * 4096 + colb] = f2b(acc[i][j][rr]);
      } else {                             // tail -> fp32
        #pragma unroll
        for (int rr = 0; rr < 4; ++rr)
          projT[(size_t)(rowb + rr) * 384 + (colb - 4096)] = acc[i][j][rr];
      }
    }
}

// ---- GEMM2: out += yb16 @ WtOutᵀ; 64x64 tile, BK=64, splitK=4, ring-3 + counted vmcnt, 1024 blocks ----
__global__ __launch_bounds__(256) void gemm2_kernel(const short* __restrict__ A, const short* __restrict__ Bt,
                                                    float* __restrict__ C){
  const int N = 1024, K = 2048;
  __shared__ __align__(16) short As[3][64 * 64];
  __shared__ __align__(16) short Bs[3][64 * 64];
  const int tid  = threadIdx.x;
  const int wave = tid >> 6;
  const int lane = tid & 63;
  // 1024 = 8 x 128 chunked swizzle
  int wg = (blockIdx.x & 7) * 128 + (blockIdx.x >> 3);
  const int m0 = (wg & 15) * 64;
  const int n0 = ((wg >> 4) & 15) * 64;
  const int k0 = (wg >> 8) * 512;
  const int wm = (wave >> 1) * 32;
  const int wn = (wave & 1) * 32;
  const int quad = lane >> 4;
  const int r16  = lane & 15;
  const int rsw  = r16 & 7;

  f4 acc[2][2];
  #pragma unroll
  for (int i = 0; i < 2; i++)
    #pragma unroll
    for (int j = 0; j < 2; j++) acc[i][j] = (f4){0.f, 0.f, 0.f, 0.f};

  const int srow = tid >> 3;
  const int soct = tid & 7;
  const int og   = (soct ^ (srow & 7)) * 8;
  const short* gA0 = A  + (size_t)(m0 + srow) * K + k0 + og;
  const short* gB0 = Bt + (size_t)(n0 + srow) * K + k0 + og;

#define G2_STAGE(buf, kt) do {                                             \
    const int ko_ = (kt) * 64;                                             \
    gload_lds16(gA0 + ko_,                  &As[buf][tid * 8]);            \
    gload_lds16(gA0 + (size_t)32 * K + ko_, &As[buf][(tid + 256) * 8]);    \
    gload_lds16(gB0 + ko_,                  &Bs[buf][tid * 8]);            \
    gload_lds16(gB0 + (size_t)32 * K + ko_, &Bs[buf][(tid + 256) * 8]);    \
  } while(0)

  G2_STAGE(0, 0);
  G2_STAGE(1, 1);

  for (int kt = 0; kt < 8; ++kt){
    if (kt < 7) asm volatile("s_waitcnt vmcnt(4)" ::: "memory");
    else        asm volatile("s_waitcnt vmcnt(0)" ::: "memory");
    __builtin_amdgcn_s_barrier();
    __builtin_amdgcn_sched_barrier(0);
    if (kt + 2 < 8){
      int nb = kt + 2 - ((kt + 2) / 3) * 3;
      G2_STAGE(nb, kt + 2);
    }
    const short* Ac = As[kt % 3];
    const short* Bc = Bs[kt % 3];
    #pragma unroll
    for (int ks = 0; ks < 2; ++ks){
      const int oq = ((ks * 4 + quad) ^ rsw) * 8;
      short8 af[2], bf[2];
      #pragma unroll
      for (int i = 0; i < 2; i++)
        af[i] = *(const short8*)&Ac[(wm + i * 16 + r16) * 64 + oq];
      #pragma unroll
      for (int j = 0; j < 2; j++)
        bf[j] = *(const short8*)&Bc[(wn + j * 16 + r16) * 64 + oq];
      #pragma unroll
      for (int i = 0; i < 2; i++)
        #pragma unroll
        for (int j = 0; j < 2; j++)
          acc[i][j] = __builtin_amdgcn_mfma_f32_16x16x32_bf16(af[i], bf[j], acc[i][j], 0, 0, 0);
    }
  }
#undef G2_STAGE

  #pragma unroll
  for (int i = 0; i < 2; i++)
    #pragma unroll
    for (int j = 0; j < 2; j++)
      #pragma unroll
      for (int rr = 0; rr < 4; ++rr){
        int row = m0 + wm + i * 16 + quad * 4 + rr;
        int col = n0 + wn + j * 16 + r16;
        unsafeAtomicAdd(&C[(size_t)row * N + col], acc[i][j][rr]);
      }
}

// ---- fused: [0,32) per-head prefix scan (Lcum/u2b/c1b) | [32,1056) theta cumsum+sincos ----
__global__ __launch_bounds__(256) void scan_theta(const float* __restrict__ projT,
                                                  const float* __restrict__ dt_bias,
                                                  float* __restrict__ Lcum, float* __restrict__ u2b,
                                                  float* __restrict__ c1b,
                                                  float* __restrict__ cosb, float* __restrict__ sinb){
  int b = blockIdx.x;
  int tid = threadIdx.x;
  int t0 = tid * 4;
  int lane = tid & 63, wave = tid >> 6;
  __shared__ float wsum[4];
  if (b < 32){
    int h = b;
    float dtbias = dt_bias[h];
    float dt5[5], lam5[5];
    #pragma unroll
    for (int i = 0; i < 5; i++){
      int t = t0 + i;
      if (t < 1024){
        const float* row = projT + (size_t)t * 384;
        dt5[i]  = softplus_f(row[256 + h] + dtbias);
        lam5[i] = 1.f / (1.f + __expf(-row[320 + h]));
      } else { dt5[i] = 0.f; lam5[i] = 0.f; }
    }
    float v[4], c1[4], c2n[4];
    #pragma unroll
    for (int i = 0; i < 4; i++){
      int t = t0 + i;
      const float* row = projT + (size_t)t * 384;
      float Ah = -fmaxf(softplus_f(row[288 + h]), 1e-4f);
      v[i]   = Ah * dt5[i];
      c1[i]  = dt5[i] * lam5[i];
      c2n[i] = dt5[i + 1] * (1.f - lam5[i + 1]);
    }
    v[1] += v[0]; v[2] += v[1]; v[3] += v[2];
    float tot = v[3], sc = tot;
    #pragma unroll
    for (int off = 1; off < 64; off <<= 1){
      float n = __shfl_up(sc, off, 64);
      if (lane >= off) sc += n;
    }
    if (lane == 63) wsum[wave] = sc;
    __syncthreads();
    float base = sc - tot;
    for (int w = 0; w < wave; ++w) base += wsum[w];
    #pragma unroll
    for (int i = 0; i < 4; i++){
      int t = t0 + i;
      Lcum[h * 1024 + t] = base + v[i];
      u2b[h * 1024 + t]  = c1[i] + c2n[i];
      c1b[h * 1024 + t]  = c1[i];
    }
  } else {
    int hk = b - 32;
    int h = hk >> 5, k = hk & 31;
    float dtbias = dt_bias[h];
    float v[4];
    #pragma unroll
    for (int i = 0; i < 4; i++){
      const float* row = projT + (size_t)(t0 + i) * 384;
      float dt = softplus_f(row[256 + h] + dtbias);
      v[i] = row[352 + k] * dt;
    }
    v[1] += v[0]; v[2] += v[1]; v[3] += v[2];
    float tot = v[3], sc = tot;
    #pragma unroll
    for (int off = 1; off < 64; off <<= 1){
      float n = __shfl_up(sc, off, 64);
      if (lane >= off) sc += n;
    }
    if (lane == 63) wsum[wave] = sc;
    __syncthreads();
    float base = sc - tot;
    for (int w = 0; w < wave; ++w) base += wsum[w];
    #pragma unroll
    for (int i = 0; i < 4; i++){
      float th = base + v[i];
      float s, c;
      __sincosf(th, &s, &c);
      int t = t0 + i;
      cosb[(size_t)t * 1024 + h * 32 + k] = c;
      sinb[(size_t)t * 1024 + h * 32 + k] = s;
    }
  }
}

// ---- rmsnorm+bias+rope -> Bb/Cb ----
__global__ __launch_bounds__(256) void bcxt_kernel(const float* __restrict__ projT,
                                                   const float* __restrict__ B_bias, const float* __restrict__ C_bias,
                                                   const float* __restrict__ Bn_w, const float* __restrict__ Cn_w,
                                                   const float* __restrict__ cosb, const float* __restrict__ sinb,
                                                   short* __restrict__ Bb, short* __restrict__ Cb){
  int t = blockIdx.x;
  int tid = threadIdx.x;
  __shared__ float vv[2][128];
  __shared__ float red[4];
  int n = tid & 127;
  int isC = tid >> 7;
  float val = projT[(size_t)t * 384 + isC * 128 + n];
  float ss = val * val;
  #pragma unroll
  for (int off = 32; off >= 1; off >>= 1) ss += __shfl_down(ss, off);
  int wave = tid >> 6, lane = tid & 63;
  if (lane == 0) red[wave] = ss;
  __syncthreads();
  float rsv = isC ? rsqrtf((red[2] + red[3]) * (1.f / 128.f) + 1e-5f)
                  : rsqrtf((red[0] + red[1]) * (1.f / 128.f) + 1e-5f);
  vv[isC][n] = val * rsv * (isC ? Cn_w[n] : Bn_w[n]);
  __syncthreads();
  const float* cb = cosb + (size_t)t * 1024;
  const float* sb = sinb + (size_t)t * 1024;
  #pragma unroll
  for (int it = 0; it < 8; it++){
    int task = tid + 256 * it;
    int arr  = task >> 10;
    int rem  = task & 1023;
    int h    = rem >> 5;
    int n0   = (rem & 31) * 4;
    const float* bias = arr ? C_bias : B_bias;
    const float* base = vv[arr];
    f4 bv = *(const f4*)&base[n0];
    f4 bi = *(const f4*)&bias[h * 128 + n0];
    f4 o;
    if (n0 < 32){
      f4 bv2 = *(const f4*)&base[n0 + 32];
      f4 bi2 = *(const f4*)&bias[h * 128 + n0 + 32];
      f4 cv = *(const f4*)&cb[h * 32 + n0];
      f4 sv = *(const f4*)&sb[h * 32 + n0];
      #pragma unroll
      for (int q = 0; q < 4; q++) o[q] = (bv[q] + bi[q]) * cv[q] - (bv2[q] + bi2[q]) * sv[q];
    } else if (n0 < 64){
      int k0 = n0 - 32;
      f4 bv1 = *(const f4*)&base[k0];
      f4 bi1 = *(const f4*)&bias[h * 128 + k0];
      f4 cv = *(const f4*)&cb[h * 32 + k0];
      f4 sv = *(const f4*)&sb[h * 32 + k0];
      #pragma unroll
      for (int q = 0; q < 4; q++) o[q] = (bv1[q] + bi1[q]) * sv[q] + (bv[q] + bi[q]) * cv[q];
    } else {
      #pragma unroll
      for (int q = 0; q < 4; q++) o[q] = bv[q] + bi[q];
    }
    uint2 pk; pk.x = pack2(o.x, o.y); pk.y = pack2(o.z, o.w);
    short* outp = arr ? Cb : Bb;
    *(uint2*)(outp + (size_t)t * 4096 + h * 128 + n0) = pk;
  }
}

// ---- per-chunk state contribution, split n-halves: 512 blocks (2/CU) ----
__global__ __launch_bounds__(256) void hpart_kernel(const short* __restrict__ xTb, const short* __restrict__ Bb,
                                                    const float* __restrict__ Lcum, const float* __restrict__ u2b,
                                                    short* __restrict__ Hpart){
  int h = blockIdx.x >> 4, c = (blockIdx.x >> 1) & 7, nh = blockIdx.x & 1;
  int t0 = c * 128;
  int tid = threadIdx.x;
  __shared__ float wS[128];
  if (tid < 128){
    float Lend = Lcum[h * 1024 + t0 + 127];
    wS[tid] = __expf(Lend - Lcum[h * 1024 + t0 + tid]) * u2b[h * 1024 + t0 + tid];
  }
  __syncthreads();
  int wave = tid >> 6, lane = tid & 63, quad = lane >> 4, r16 = lane & 15;
  int n0 = nh * 64 + wave * 16;
  f4 acc[4];
  #pragma unroll
  for (int i = 0; i < 4; i++) acc[i] = (f4){0.f, 0.f, 0.f, 0.f};

  const ushort* Bh = (const ushort*)Bb + (size_t)t0 * 4096 + h * 128;
  #pragma unroll
  for (int kk = 0; kk < 4; ++kk){
    int sb = kk * 32 + quad * 8;
    short8 af[4];
    #pragma unroll
    for (int i = 0; i < 4; i++){
      int p = i * 16 + r16;
      af[i] = *(const short8*)(xTb + (size_t)(h * 64 + p) * 1024 + t0 + sb);
    }
    float wv[8];
    #pragma unroll
    for (int jj = 0; jj < 8; jj++) wv[jj] = wS[sb + jj];
    int nn = n0 + r16;
    float e[8];
    #pragma unroll
    for (int jj = 0; jj < 8; jj++)
      e[jj] = b2f(Bh[(size_t)(sb + jj) * 4096 + nn]) * wv[jj];
    union { short8 s; uint32_t u[4]; } fr;
    #pragma unroll
    for (int q = 0; q < 4; q++) fr.u[q] = pack2(e[2 * q], e[2 * q + 1]);
    short8 bfr = fr.s;
    #pragma unroll
    for (int i = 0; i < 4; i++)
      acc[i] = __builtin_amdgcn_mfma_f32_16x16x32_bf16(af[i], bfr, acc[i], 0, 0, 0);
  }

  short* out = Hpart + ((size_t)(h * 8 + c)) * 8192;
  int nn = n0 + r16;
  #pragma unroll
  for (int i = 0; i < 4; i++)
    #pragma unroll
    for (int rr = 0; rr < 4; ++rr){
      int p = i * 16 + quad * 4 + rr;
      out[p * 128 + nn] = f2b(acc[i][rr]);
    }
}

// ---- chunked dual + fused hscan, split trow-halves: 512 blocks (~36KB LDS, 2/CU) ----
#define GS 144
__global__ __launch_bounds__(256) void chunky_kernel(const short* __restrict__ Cb, const short* __restrict__ Bbg,
                                                     const short* __restrict__ xTb, const short* __restrict__ Hpart,
                                                     const float* __restrict__ Lcum, const float* __restrict__ u2b,
                                                     const float* __restrict__ c1b,
                                                     const short* __restrict__ zx, const float* __restrict__ D_par,
                                                     short* __restrict__ yb16){
  int h = blockIdx.x >> 4, c = (blockIdx.x >> 1) & 7, half = blockIdx.x & 1;
  int t0 = c * 128;
  int tb = half * 64;                              // trow base within chunk
  __shared__ __align__(16) short Gt[64 * GS];
  __shared__ __align__(16) short Hu[64 * 128];     // XOR-swizzled: byte ^= (row&7)<<4
  __shared__ float Lc[128], u2v[128], c1v[128];
  int tid = threadIdx.x;
  if (tid < 128){
    Lc[tid]  = Lcum[h * 1024 + t0 + tid];
    u2v[tid] = u2b[h * 1024 + t0 + tid];
    c1v[tid] = c1b[h * 1024 + t0 + tid];
  }
  float Lprev = (c > 0) ? Lcum[h * 1024 + t0 - 1] : 0.f;
  float Dp = D_par[h];

  // ---- fused hscan: decay-sum of previous chunks into Hu (redundant per half, cheap) ----
  {
    float hacc[32];
    #pragma unroll
    for (int q = 0; q < 32; q++) hacc[q] = 0.f;
    for (int cp = 0; cp < c; ++cp){
      float dec = __expf(Lprev - Lcum[h * 1024 + cp * 128 + 127]);
      const short8* hp = (const short8*)((const ushort*)Hpart + ((size_t)(h * 8 + cp)) * 8192 + tid * 32);
      #pragma unroll
      for (int q = 0; q < 4; q++){
        short8 v = hp[q];
        #pragma unroll
        for (int e = 0; e < 8; e++) hacc[q * 8 + e] += dec * b2f((uint16_t)v[e]);
      }
    }
    int p = tid >> 2;                                // row (0..63), constant per thread
    int wbase = tid * 64;                            // byte base in Hu
    #pragma unroll
    for (int q = 0; q < 4; q++){
      union { short8 s; uint32_t u[4]; } fr;
      #pragma unroll
      for (int p2 = 0; p2 < 4; p2++) fr.u[p2] = pack2(hacc[q * 8 + p2 * 2], hacc[q * 8 + p2 * 2 + 1]);
      int off = (wbase + q * 16) ^ ((p & 7) << 4);
      *(short8*)((char*)Hu + off) = fr.s;
    }
  }

  int wave = tid >> 6, lane = tid & 63, quad = lane >> 4, r16 = lane & 15;
  // S phase: 64 trows x 128 scols, waves 2x2: wm2 in {0,32}, wn2 in {0,64}
  int wm2 = (wave >> 1) * 32, wn2 = (wave & 1) * 64;

  f4 acc[2][4];
  #pragma unroll
  for (int i = 0; i < 2; i++)
    #pragma unroll
    for (int j = 0; j < 4; j++) acc[i][j] = (f4){0.f, 0.f, 0.f, 0.f};
  #pragma unroll
  for (int kk = 0; kk < 4; ++kk){
    short8 af[2], bf[4];
    #pragma unroll
    for (int i = 0; i < 2; i++)
      af[i] = *(const short8*)(Cb + (size_t)(t0 + tb + wm2 + i * 16 + r16) * 4096 + h * 128 + kk * 32 + quad * 8);
    #pragma unroll
    for (int j = 0; j < 4; j++)
      bf[j] = *(const short8*)(Bbg + (size_t)(t0 + wn2 + j * 16 + r16) * 4096 + h * 128 + kk * 32 + quad * 8);
    #pragma unroll
    for (int i = 0; i < 2; i++)
      #pragma unroll
      for (int j = 0; j < 4; j++)
        acc[i][j] = __builtin_amdgcn_mfma_f32_16x16x32_bf16(af[i], bf[j], acc[i][j], 0, 0, 0);
  }
  __syncthreads();   // covers Lc/u2v/c1v and Hu writes

  #pragma unroll
  for (int i = 0; i < 2; i++){
    #pragma unroll
    for (int rr = 0; rr < 4; ++rr){
      int tl = wm2 + i * 16 + quad * 4 + rr;       // local trow 0..63
      int trow = tb + tl;
      float Lt = Lc[trow];
      #pragma unroll
      for (int j = 0; j < 4; j++){
        int scol = wn2 + j * 16 + r16;
        float g = 0.f;
        if (scol <= trow){
          float wcoef = (scol == trow) ? c1v[scol] : u2v[scol];
          g = acc[i][j][rr] * wcoef * __expf(Lt - Lc[scol]);
        }
        Gt[tl * GS + scol] = f2b(g);
      }
    }
  }
  __syncthreads();

  // Y phase: each wave owns 16 trows
  f4 accY[4], accZ[4];
  #pragma unroll
  for (int j = 0; j < 4; j++){ accY[j] = (f4){0.f,0.f,0.f,0.f}; accZ[j] = (f4){0.f,0.f,0.f,0.f}; }
  int m0 = wave * 16;
  #pragma unroll
  for (int kk = 0; kk < 4; ++kk){
    short8 ag, ac, bx[4], bh[4];
    ag = *(const short8*)&Gt[(m0 + r16) * GS + kk * 32 + quad * 8];
    ac = *(const short8*)(Cb + (size_t)(t0 + tb + m0 + r16) * 4096 + h * 128 + kk * 32 + quad * 8);
    #pragma unroll
    for (int j = 0; j < 4; j++){
      bx[j] = *(const short8*)(xTb + (size_t)(h * 64 + j * 16 + r16) * 1024 + t0 + kk * 32 + quad * 8);
      int hrow = j * 16 + r16;
      int hoff = (hrow * 256 + kk * 64 + quad * 16) ^ ((hrow & 7) << 4);
      bh[j] = *(const short8*)((const char*)Hu + hoff);
    }
    #pragma unroll
    for (int j = 0; j < 4; j++){
      accY[j] = __builtin_amdgcn_mfma_f32_16x16x32_bf16(ag, bx[j], accY[j], 0, 0, 0);
      accZ[j] = __builtin_amdgcn_mfma_f32_16x16x32_bf16(ac, bh[j], accZ[j], 0, 0, 0);
    }
  }
  // fused post: y = (y + D*x) * silu(z), cast bf16
  const ushort* zxu = (const ushort*)zx;
  #pragma unroll
  for (int rr = 0; rr < 4; ++rr){
    int tl = m0 + quad * 4 + rr;
    int trow = tb + tl;
    float ei = __expf(Lc[trow] - Lprev);
    const ushort* zrow = zxu + (size_t)(t0 + trow) * 4096;
    #pragma unroll
    for (int j = 0; j < 4; j++){
      int col = h * 64 + j * 16 + r16;
      float zv = b2f(zrow[col]);
      float xv = b2f(zrow[2048 + col]);
      float yv = accY[j][rr] + ei * accZ[j][rr] + Dp * xv;
      float o = yv * (zv / (1.f + __expf(-zv)));
      yb16[(size_t)(t0 + trow) * 2048 + col] = f2b(o);
    }
  }
}

extern "C" void kernel_launch(void* const* d_in, const int* in_sizes, int n_in,
                              void* d_out, int out_size, void* d_ws, size_t ws_size,
                              hipStream_t stream){
  const float* u       = (const float*)d_in[0];
  const float* W_in    = (const float*)d_in[1];
  const float* dt_bias = (const float*)d_in[2];
  const float* B_bias  = (const float*)d_in[3];
  const float* C_bias  = (const float*)d_in[4];
  const float* Bn_w    = (const float*)d_in[5];
  const float* Cn_w    = (const float*)d_in[6];
  const float* D_par   = (const float*)d_in[7];
  const float* W_out   = (const float*)d_in[8];
  float* out = (float*)d_out;

  char* ws = (char*)d_ws;
  short* u16   = (short*)(ws + 0);          // 2,097,152
  short* WtIn  = (short*)(ws + 2097152);    // 9,175,040
  short* WtOut = (short*)(ws + 11272192);   // 4,194,304
  short* zx    = (short*)(ws + 15466496);   // 8,388,608
  float* projT = (float*)(ws + 23855104);   // 1,572,864
  float* cosb  = (float*)(ws + 25427968);   // 4,194,304
  float* sinb  = (float*)(ws + 29622272);   // 4,194,304
  short* Bb    = (short*)(ws + 33816576);   // 8,388,608
  short* Cb    = (short*)(ws + 42205184);   // 8,388,608
  short* xTb   = (short*)(ws + 50593792);   // 4,194,304
  float* Lcum  = (float*)(ws + 54788096);   // 131,072
  float* u2b   = (float*)(ws + 54919168);   // 131,072
  float* c1b   = (float*)(ws + 55050240);   // 131,072
  short* Hpart = (short*)(ws + 55181312);   // 4,194,304
  short* yb16  = (short*)(ws + 59375616);   // 4,194,304 -> total 63,569,920 B

  prep_inputs<<<3680, 256, 0, stream>>>(u, u16, W_in, WtIn, W_out, WtOut, out);
  gemm1_kernel<<<1120, 256, 0, stream>>>(u16, WtIn, zx, xTb, projT);
  scan_theta<<<1056, 256, 0, stream>>>(projT, dt_bias, Lcum, u2b, c1b, cosb, sinb);
  bcxt_kernel<<<1024, 256, 0, stream>>>(projT, B_bias, C_bias, Bn_w, Cn_w, cosb, sinb, Bb, Cb);
  hpart_kernel<<<512, 256, 0, stream>>>(xTb, Bb, Lcum, u2b, Hpart);
  chunky_kernel<<<512, 256, 0, stream>>>(Cb, Bb, xTb, Hpart, Lcum, u2b, c1b, zx, D_par, yb16);
  gemm2_kernel<<<1024, 256, 0, stream>>>(yb16, WtOut, out);
}